// Round 1
// baseline (108.755 us; speedup 1.0000x reference)
//
#include <hip/hip_runtime.h>

#define B_SZ 4096
#define F_N  39
#define V_N  100000
#define D_N  16
#define H_N  400
#define K1_N 624   // F*D

// -------------------- kernel 1: gather + fst + FM --------------------
__global__ __launch_bounds__(640) void gather_kernel(
    const int*   __restrict__ Xi,
    const float* __restrict__ Xv,
    const float* __restrict__ fst_t,
    const float* __restrict__ sec_t,
    const float* __restrict__ bias,
    float* __restrict__ sec_flat,
    float* __restrict__ out)
{
    const int b   = blockIdx.x;
    const int tid = threadIdx.x;

    __shared__ float smem[K1_N];
    __shared__ float red[10];
    __shared__ int   sidx[F_N];
    __shared__ float sval[F_N];

    if (tid < F_N) {
        sidx[tid] = Xi[b * F_N + tid];
        sval[tid] = Xv[b * F_N + tid];
    }
    __syncthreads();

    float sumsq = 0.f;
    if (tid < K1_N) {
        const int f = tid >> 4, d = tid & 15;
        const float val = sval[f];
        const float v = sec_t[((long long)f * V_N + sidx[f]) * D_N + d] * val;
        smem[tid] = v;
        sec_flat[(long long)b * K1_N + tid] = v;
        sumsq = v * v;
    }
    // wave-reduce sumsq (wave = 64)
    for (int off = 32; off; off >>= 1) sumsq += __shfl_down(sumsq, off, 64);
    if ((tid & 63) == 0) red[tid >> 6] = sumsq;
    __syncthreads();

    if (tid < 64) {
        float fs = 0.f;
        if (tid < F_N)
            fs = fst_t[(long long)tid * V_N + sidx[tid]] * sval[tid];
        float fm = 0.f;
        if (tid < D_N) {
            float s = 0.f;
            #pragma unroll
            for (int f = 0; f < F_N; ++f) s += smem[f * D_N + tid];
            fm = 0.5f * s * s;
        }
        float t = fs + fm;
        for (int off = 32; off; off >>= 1) t += __shfl_down(t, off, 64);
        if (tid == 0) {
            float sq = 0.f;
            #pragma unroll
            for (int w = 0; w < 10; ++w) sq += red[w];
            out[b] = t - 0.5f * sq + bias[0];
        }
    }
}

// -------------------- tiled fp32 GEMM, 64x64 tile, BK=16, 4x4/thread ----
// C = relu(A @ Bw + bias); if ROWSUM: atomicAdd per-row sums into out instead
template <bool ROWSUM>
__global__ __launch_bounds__(256) void gemm_relu(
    const float* __restrict__ A,
    const float* __restrict__ Bw,
    const float* __restrict__ bias,
    float* __restrict__ C,
    float* __restrict__ out,
    int M, int N, int K)
{
    __shared__ float As[64][17];
    __shared__ float Bs[16][64];

    const int tid  = threadIdx.x;
    const int bc   = blockIdx.x;  // col tile
    const int br   = blockIdx.y;  // row tile
    const int row0 = br * 64;
    const int col0 = bc * 64;
    const int tx   = tid & 15;
    const int ty   = tid >> 4;

    float acc[4][4] = {};

    const int arow = tid >> 2;        // 0..63
    const int akq  = (tid & 3) * 4;   // 0,4,8,12
    const int bkr  = tid >> 4;        // 0..15
    const int bcq  = (tid & 15) * 4;  // 0..60

    for (int k0 = 0; k0 < K; k0 += 16) {
        // A tile (always in-bounds: M%64==0, K%16==0)
        const float4 av = *(const float4*)(A + (long long)(row0 + arow) * K + k0 + akq);
        As[arow][akq + 0] = av.x;
        As[arow][akq + 1] = av.y;
        As[arow][akq + 2] = av.z;
        As[arow][akq + 3] = av.w;
        // B tile (guard cols vs N)
        const int gc = col0 + bcq;
        float4 bv;
        if (gc + 3 < N) {
            bv = *(const float4*)(Bw + (long long)(k0 + bkr) * N + gc);
        } else {
            const float* bp = Bw + (long long)(k0 + bkr) * N;
            bv.x = (gc + 0 < N) ? bp[gc + 0] : 0.f;
            bv.y = (gc + 1 < N) ? bp[gc + 1] : 0.f;
            bv.z = (gc + 2 < N) ? bp[gc + 2] : 0.f;
            bv.w = (gc + 3 < N) ? bp[gc + 3] : 0.f;
        }
        *(float4*)&Bs[bkr][bcq] = bv;
        __syncthreads();

        #pragma unroll
        for (int k = 0; k < 16; ++k) {
            float a0 = As[ty * 4 + 0][k];
            float a1 = As[ty * 4 + 1][k];
            float a2 = As[ty * 4 + 2][k];
            float a3 = As[ty * 4 + 3][k];
            float b0 = Bs[k][tx * 4 + 0];
            float b1 = Bs[k][tx * 4 + 1];
            float b2 = Bs[k][tx * 4 + 2];
            float b3 = Bs[k][tx * 4 + 3];
            acc[0][0] += a0 * b0; acc[0][1] += a0 * b1; acc[0][2] += a0 * b2; acc[0][3] += a0 * b3;
            acc[1][0] += a1 * b0; acc[1][1] += a1 * b1; acc[1][2] += a1 * b2; acc[1][3] += a1 * b3;
            acc[2][0] += a2 * b0; acc[2][1] += a2 * b1; acc[2][2] += a2 * b2; acc[2][3] += a2 * b3;
            acc[3][0] += a3 * b0; acc[3][1] += a3 * b1; acc[3][2] += a3 * b2; acc[3][3] += a3 * b3;
        }
        __syncthreads();
    }

    if constexpr (ROWSUM) {
        __shared__ float rsum[64][17];
        float rs[4] = {0.f, 0.f, 0.f, 0.f};
        #pragma unroll
        for (int i = 0; i < 4; ++i) {
            #pragma unroll
            for (int j = 0; j < 4; ++j) {
                const int gc = col0 + tx * 4 + j;
                if (gc < N) {
                    const float vv = acc[i][j] + bias[gc];
                    rs[i] += fmaxf(vv, 0.f);
                }
            }
        }
        #pragma unroll
        for (int i = 0; i < 4; ++i) rsum[ty * 4 + i][tx] = rs[i];
        __syncthreads();
        if (tid < 64) {
            float s = 0.f;
            #pragma unroll
            for (int t = 0; t < 16; ++t) s += rsum[tid][t];
            atomicAdd(out + row0 + tid, s);
        }
    } else {
        #pragma unroll
        for (int i = 0; i < 4; ++i) {
            const int gr = row0 + ty * 4 + i;
            const int gc0 = col0 + tx * 4;
            if (gc0 + 3 < N) {
                float4 v;
                v.x = fmaxf(acc[i][0] + bias[gc0 + 0], 0.f);
                v.y = fmaxf(acc[i][1] + bias[gc0 + 1], 0.f);
                v.z = fmaxf(acc[i][2] + bias[gc0 + 2], 0.f);
                v.w = fmaxf(acc[i][3] + bias[gc0 + 3], 0.f);
                *(float4*)(C + (long long)gr * N + gc0) = v;
            } else {
                #pragma unroll
                for (int j = 0; j < 4; ++j) {
                    const int gc = gc0 + j;
                    if (gc < N)
                        C[(long long)gr * N + gc] = fmaxf(acc[i][j] + bias[gc], 0.f);
                }
            }
        }
    }
}

extern "C" void kernel_launch(void* const* d_in, const int* in_sizes, int n_in,
                              void* d_out, int out_size, void* d_ws, size_t ws_size,
                              hipStream_t stream)
{
    const int*   Xi    = (const int*)  d_in[0];
    const float* Xv    = (const float*)d_in[1];
    const float* fst_t = (const float*)d_in[2];
    const float* sec_t = (const float*)d_in[3];
    const float* W1    = (const float*)d_in[4];
    const float* b1    = (const float*)d_in[5];
    const float* W2    = (const float*)d_in[6];
    const float* b2    = (const float*)d_in[7];
    const float* bias  = (const float*)d_in[8];

    float* out      = (float*)d_out;
    float* ws       = (float*)d_ws;
    float* sec_flat = ws;                                  // 4096*624 floats
    float* h        = ws + (size_t)B_SZ * K1_N;            // 4096*400 floats

    gather_kernel<<<B_SZ, 640, 0, stream>>>(Xi, Xv, fst_t, sec_t, bias, sec_flat, out);

    dim3 grid((H_N + 63) / 64, B_SZ / 64);   // (7, 64)
    dim3 blk(256);
    gemm_relu<false><<<grid, blk, 0, stream>>>(sec_flat, W1, b1, h, nullptr, B_SZ, H_N, K1_N);
    gemm_relu<true ><<<grid, blk, 0, stream>>>(h, W2, b2, nullptr, out, B_SZ, H_N, H_N);
}

// Round 2
// 41.779 us; speedup vs baseline: 2.6031x; 2.6031x over previous
//
#include <hip/hip_runtime.h>
#include <hip/hip_bf16.h>

#define B_SZ 4096
#define F_N  39
#define V_N  100000
#define D_N  16
#define H_N  400
#define K1   624      // F*D
#define K1P  640      // K1 padded to mult of 64
#define NP   512      // H padded to mult of 64

typedef __attribute__((ext_vector_type(8))) short short8;
typedef __attribute__((ext_vector_type(4))) float f32x4;

typedef const __attribute__((address_space(1))) void g_void;
typedef __attribute__((address_space(3))) void l_void;

// -------------------- kernel 1: gather + fst + FM + bf16 sec_flat ------------
__global__ __launch_bounds__(640) void gather_kernel(
    const int*   __restrict__ Xi,
    const float* __restrict__ Xv,
    const float* __restrict__ fst_t,
    const float* __restrict__ sec_t,
    const float* __restrict__ bias,
    __hip_bfloat16* __restrict__ sec_flat,
    float* __restrict__ out)
{
    const int b   = blockIdx.x;
    const int tid = threadIdx.x;

    __shared__ float smem[K1];
    __shared__ float red[10];
    __shared__ int   sidx[F_N];
    __shared__ float sval[F_N];

    if (tid < F_N) {
        sidx[tid] = Xi[b * F_N + tid];
        sval[tid] = Xv[b * F_N + tid];
    }
    __syncthreads();

    float sumsq = 0.f;
    float v = 0.f;
    if (tid < K1) {
        const int f = tid >> 4;
        const int d = tid & 15;
        v = sec_t[((long long)f * V_N + sidx[f]) * D_N + d] * sval[f];
        smem[tid] = v;
        sumsq = v * v;
    }
    sec_flat[(size_t)b * K1P + tid] = __float2bfloat16(v);  // cols 624..639 -> 0

    for (int off = 32; off; off >>= 1) sumsq += __shfl_down(sumsq, off, 64);
    if ((tid & 63) == 0) red[tid >> 6] = sumsq;
    __syncthreads();

    if (tid < 64) {
        float fs = 0.f;
        if (tid < F_N)
            fs = fst_t[(long long)tid * V_N + sidx[tid]] * sval[tid];
        float fm = 0.f;
        if (tid < D_N) {
            float s = 0.f;
            #pragma unroll
            for (int f = 0; f < F_N; ++f) s += smem[f * D_N + tid];
            fm = 0.5f * s * s;
        }
        float t = fs + fm;
        for (int off = 32; off; off >>= 1) t += __shfl_down(t, off, 64);
        if (tid == 0) {
            float sq = 0.f;
            #pragma unroll
            for (int w = 0; w < 10; ++w) sq += red[w];
            out[b] = t - 0.5f * sq + bias[0];
        }
    }
}

// ------------- kernel 2: weight transpose+pad+bf16 convert -------------------
// W1t[n][k] (NP x K1P), W2t[n][k] (NP x NP), b1p/b2p padded to NP
#define CVT_W1  (NP * K1P)
#define CVT_W2  (NP * NP)
#define CVT_TOT (CVT_W1 + CVT_W2 + NP + NP)
__global__ __launch_bounds__(256) void convert_kernel(
    const float* __restrict__ W1, const float* __restrict__ b1,
    const float* __restrict__ W2, const float* __restrict__ b2,
    __hip_bfloat16* __restrict__ W1t, __hip_bfloat16* __restrict__ W2t,
    float* __restrict__ b1p, float* __restrict__ b2p)
{
    int i = blockIdx.x * 256 + threadIdx.x;
    if (i < CVT_W1) {
        const int n = i / K1P, k = i % K1P;
        W1t[i] = __float2bfloat16((n < H_N && k < K1) ? W1[k * H_N + n] : 0.f);
        return;
    }
    i -= CVT_W1;
    if (i < CVT_W2) {
        const int n = i / NP, k = i % NP;
        W2t[i] = __float2bfloat16((n < H_N && k < H_N) ? W2[k * H_N + n] : 0.f);
        return;
    }
    i -= CVT_W2;
    if (i < NP) { b1p[i] = (i < H_N) ? b1[i] : 0.f; return; }
    i -= NP;
    if (i < NP) { b2p[i] = (i < H_N) ? b2[i] : 0.f; }
}

// ------------- kernel 3/4: bf16 MFMA GEMM, 64x64 tile, BK=64 -----------------
// C = relu(A @ Bt^T + bias)   (A: [M][KT] bf16, Bt: [NP][KT] bf16 = W^T)
// ROWSUM: atomicAdd per-row sums of relu(...) into out instead of storing C
template <int KT, bool ROWSUM>
__global__ __launch_bounds__(256) void mfma_gemm(
    const __hip_bfloat16* __restrict__ A,
    const __hip_bfloat16* __restrict__ Bt,
    const float* __restrict__ bias,
    __hip_bfloat16* __restrict__ C,
    float* __restrict__ out)
{
    __shared__ __align__(16) __hip_bfloat16 As[64 * 64];
    __shared__ __align__(16) __hip_bfloat16 Bs[64 * 64];

    const int tid  = threadIdx.x;
    const int lane = tid & 63;
    const int wid  = tid >> 6;           // 4 waves: 2 (M) x 2 (N)
    const int wm   = wid >> 1;
    const int wn   = wid & 1;
    const int row0 = blockIdx.y * 64;
    const int col0 = blockIdx.x * 64;
    const int lr   = lane & 15;          // frag row/col
    const int lk   = (lane >> 4) * 8;    // frag k-offset

    f32x4 acc[2][2] = {};

    const int sr = tid >> 3;             // staging row 0..31
    const int sc = (tid & 7) * 8;        // staging col chunk (8 bf16 = 16 B)

    for (int k0 = 0; k0 < KT; k0 += 64) {
        if (k0) __syncthreads();         // all waves done reading prev tile
        #pragma unroll
        for (int i = 0; i < 2; ++i) {
            __builtin_amdgcn_global_load_lds(
                (g_void*)(A + (size_t)(row0 + i * 32 + sr) * KT + k0 + sc),
                (l_void*)(As + (i * 32 + sr) * 64 + sc), 16, 0, 0);
            __builtin_amdgcn_global_load_lds(
                (g_void*)(Bt + (size_t)(col0 + i * 32 + sr) * KT + k0 + sc),
                (l_void*)(Bs + (i * 32 + sr) * 64 + sc), 16, 0, 0);
        }
        __syncthreads();                 // vmcnt(0) drain + barrier: tile ready

        #pragma unroll
        for (int ks = 0; ks < 2; ++ks) {
            short8 a[2], bb[2];
            #pragma unroll
            for (int m = 0; m < 2; ++m)
                a[m] = *(const short8*)(As + (wm * 32 + m * 16 + lr) * 64 + ks * 32 + lk);
            #pragma unroll
            for (int n = 0; n < 2; ++n)
                bb[n] = *(const short8*)(Bs + (wn * 32 + n * 16 + lr) * 64 + ks * 32 + lk);
            #pragma unroll
            for (int m = 0; m < 2; ++m)
                #pragma unroll
                for (int n = 0; n < 2; ++n)
                    acc[m][n] = __builtin_amdgcn_mfma_f32_16x16x32_bf16(
                        a[m], bb[n], acc[m][n], 0, 0, 0);
        }
    }

    // epilogue — C/D layout: col = lane&15, row = (lane>>4)*4 + reg  [m89]
    if constexpr (!ROWSUM) {
        #pragma unroll
        for (int m = 0; m < 2; ++m) {
            const int row = row0 + wm * 32 + m * 16 + (lane >> 4) * 4;
            #pragma unroll
            for (int n = 0; n < 2; ++n) {
                const int col = col0 + wn * 32 + n * 16 + lr;
                const float bv = bias[col];
                #pragma unroll
                for (int r = 0; r < 4; ++r)
                    C[(size_t)(row + r) * NP + col] =
                        __float2bfloat16(fmaxf(acc[m][n][r] + bv, 0.f));
            }
        }
    } else {
        #pragma unroll
        for (int m = 0; m < 2; ++m) {
            float v[4] = {0.f, 0.f, 0.f, 0.f};
            #pragma unroll
            for (int n = 0; n < 2; ++n) {
                const int col = col0 + wn * 32 + n * 16 + lr;
                const float bv = bias[col];
                #pragma unroll
                for (int r = 0; r < 4; ++r)
                    v[r] += fmaxf(acc[m][n][r] + bv, 0.f);
            }
            // reduce across the 16 cols (lanes lr=0..15 within each lane>>4 group)
            #pragma unroll
            for (int off = 1; off < 16; off <<= 1)
                #pragma unroll
                for (int r = 0; r < 4; ++r)
                    v[r] += __shfl_xor(v[r], off, 64);
            if (lr == 0) {
                const int row = row0 + wm * 32 + m * 16 + (lane >> 4) * 4;
                #pragma unroll
                for (int r = 0; r < 4; ++r)
                    atomicAdd(out + row + r, v[r]);
            }
        }
    }
}

extern "C" void kernel_launch(void* const* d_in, const int* in_sizes, int n_in,
                              void* d_out, int out_size, void* d_ws, size_t ws_size,
                              hipStream_t stream)
{
    const int*   Xi    = (const int*)  d_in[0];
    const float* Xv    = (const float*)d_in[1];
    const float* fst_t = (const float*)d_in[2];
    const float* sec_t = (const float*)d_in[3];
    const float* W1    = (const float*)d_in[4];
    const float* b1    = (const float*)d_in[5];
    const float* W2    = (const float*)d_in[6];
    const float* b2    = (const float*)d_in[7];
    const float* bias  = (const float*)d_in[8];

    float* out = (float*)d_out;
    char*  wsb = (char*)d_ws;

    // ws layout (bytes)
    __hip_bfloat16* sec_flat = (__hip_bfloat16*)(wsb);                 // 4096*640*2 = 5,242,880
    __hip_bfloat16* h        = (__hip_bfloat16*)(wsb + 5242880);       // 4096*512*2 = 4,194,304
    __hip_bfloat16* W1t      = (__hip_bfloat16*)(wsb + 9437184);       // 512*640*2  =   655,360
    __hip_bfloat16* W2t      = (__hip_bfloat16*)(wsb + 10092544);      // 512*512*2  =   524,288
    float*          b1p      = (float*)(wsb + 10616832);               // 512*4
    float*          b2p      = (float*)(wsb + 10618880);               // 512*4

    gather_kernel<<<B_SZ, 640, 0, stream>>>(Xi, Xv, fst_t, sec_t, bias, sec_flat, out);
    convert_kernel<<<(CVT_TOT + 255) / 256, 256, 0, stream>>>(W1, b1, W2, b2, W1t, W2t, b1p, b2p);

    dim3 grid(NP / 64, B_SZ / 64);   // (8, 64) = 512 blocks
    mfma_gemm<K1P, false><<<grid, 256, 0, stream>>>(sec_flat, W1t, b1p, h, nullptr);
    mfma_gemm<NP,  true ><<<grid, 256, 0, stream>>>(h, W2t, b2p, nullptr, out);
}